// Round 1
// baseline (48.971 us; speedup 1.0000x reference)
//
#include <hip/hip_runtime.h>

// Problem geometry (fixed by setup_inputs): b=16, n=32, h=w=256.
#define B 16
#define N 32
#define HW 65536          // 256*256
#define CHUNKS 4          // chunks per (b,n) pair
#define CHUNK (HW / CHUNKS) // 16384 elements per block
#define PAIRS (B * N)     // 512

__global__ __launch_bounds__(256) void iou_partial_kernel(
    const float* __restrict__ pd, const float* __restrict__ gt,
    const int* __restrict__ pdm, const int* __restrict__ gtm,
    float2* __restrict__ ws)
{
    const int blk   = blockIdx.x;        // 0..2047
    const int pair  = blk >> 2;          // b*N + n
    const int chunk = blk & 3;
    const int b     = pair >> 5;         // pair / N

    const int base = chunk * CHUNK;
    const float4* __restrict__ pdp = (const float4*)(pd + (size_t)b * HW + base);
    const float4* __restrict__ gtp = (const float4*)(gt + (size_t)b * HW + base);
    const int4*   __restrict__ pmp = (const int4*)(pdm + (size_t)pair * HW + base);
    const int4*   __restrict__ gmp = (const int4*)(gtm + (size_t)pair * HW + base);

    float inter = 0.0f, uni = 0.0f;
    const int t = threadIdx.x;

    // CHUNK/4 = 4096 float4s, 256 threads -> 16 iterations, coalesced 16B/lane
    #pragma unroll 4
    for (int i = t; i < CHUNK / 4; i += 256) {
        float4 p = pdp[i];
        float4 g = gtp[i];
        int4  pm = pmp[i];
        int4  gm = gmp[i];

        // masks are {0,1}: and = pm&gm, pd-only = pm&~gm
        inter += (pm.x & gm.x) ? p.x : 0.0f;
        inter += (pm.y & gm.y) ? p.y : 0.0f;
        inter += (pm.z & gm.z) ? p.z : 0.0f;
        inter += (pm.w & gm.w) ? p.w : 0.0f;

        uni += (gm.x ? g.x : 0.0f) + ((pm.x & ~gm.x) ? p.x : 0.0f);
        uni += (gm.y ? g.y : 0.0f) + ((pm.y & ~gm.y) ? p.y : 0.0f);
        uni += (gm.z ? g.z : 0.0f) + ((pm.z & ~gm.z) ? p.z : 0.0f);
        uni += (gm.w ? g.w : 0.0f) + ((pm.w & ~gm.w) ? p.w : 0.0f);
    }

    // wave64 butterfly reduce
    #pragma unroll
    for (int o = 32; o > 0; o >>= 1) {
        inter += __shfl_down(inter, o, 64);
        uni   += __shfl_down(uni, o, 64);
    }

    __shared__ float s_i[4], s_u[4];
    const int wave = t >> 6, lane = t & 63;
    if (lane == 0) { s_i[wave] = inter; s_u[wave] = uni; }
    __syncthreads();
    if (t == 0) {
        float I = s_i[0] + s_i[1] + s_i[2] + s_i[3];
        float U = s_u[0] + s_u[1] + s_u[2] + s_u[3];
        ws[blk] = make_float2(I, U);
    }
}

__global__ __launch_bounds__(512) void iou_final_kernel(
    const float2* __restrict__ ws, float* __restrict__ out)
{
    const int t = threadIdx.x; // one thread per (b,n) pair, 512 threads
    float I = 0.0f, U = 0.0f;
    #pragma unroll
    for (int c = 0; c < CHUNKS; ++c) {
        float2 v = ws[t * CHUNKS + c];
        I += v.x; U += v.y;
    }
    float loss = I / (U + 1e-6f);

    #pragma unroll
    for (int o = 32; o > 0; o >>= 1)
        loss += __shfl_down(loss, o, 64);

    __shared__ float s[8];
    const int wave = t >> 6, lane = t & 63;
    if (lane == 0) s[wave] = loss;
    __syncthreads();
    if (t == 0) {
        float sum = 0.0f;
        #pragma unroll
        for (int w = 0; w < 8; ++w) sum += s[w];
        out[0] = 1.0f - sum / (float)PAIRS;
    }
}

extern "C" void kernel_launch(void* const* d_in, const int* in_sizes, int n_in,
                              void* d_out, int out_size, void* d_ws, size_t ws_size,
                              hipStream_t stream) {
    const float* pd  = (const float*)d_in[0];
    const float* gt  = (const float*)d_in[1];
    const int*   pdm = (const int*)d_in[2];
    const int*   gtm = (const int*)d_in[3];
    float* out = (float*)d_out;
    float2* ws = (float2*)d_ws;   // PAIRS*CHUNKS float2 = 16 KB

    iou_partial_kernel<<<PAIRS * CHUNKS, 256, 0, stream>>>(pd, gt, pdm, gtm, ws);
    iou_final_kernel<<<1, 512, 0, stream>>>(ws, out);
}